// Round 9
// baseline (232.741 us; speedup 1.0000x reference)
//
#include <hip/hip_runtime.h>
#include <hip/hip_fp16.h>

// GCN 4-layer: 29->96->128->64->32, N=50000, E=800000 (+self loops).
// Round 28 = r27 (210.8 us) with place_x rebuilt as a SINGLE-PASS scan
// (G=1, no XCD-group filter). The 8-group XCD-affine build read the edge
// list 8x (~100 MB) to keep atomics XCD-local; but every other XCD-locality
// hypothesis this session (gather affinity r20/r22, clean-vs-dirty r26,
// line-sharing r27) was falsified, so test the last one: do counter atomics
// care about issuing-XCD locality? Single pass: edge reads 12.8 MB (8x
// less), same 800K atomics, now from all XCDs. Counter padding (CST=32,
// cost-neutral, r27) kept - removes cross-XCD false sharing under the new
// write pattern. Everything downstream byte-identical.
// If neutral-atomics: place_x 44 -> ~18 us, total ~188. If locality real:
// place_x balloons -> revert + take G=2 / fp16-pre-agg next.
// Structure: collapsed layers 2-4 (out = A^3(h1 W234)+c2 v2+c1 v1+b4),
// u16 ELL + 8-index int4 gathers, fp16 hop intermediates (16B/lane,
// edge-parity split, shfl merge), weight collapse riding prep/agg_pre.
// 8 dispatches. No cooperative launches.
// NOTE: harness delivers integer inputs as int32.

constexpr int NN  = 50000;
constexpr int CAP = 64;    // max in-degree; Poisson(16) over 50K => P(>=64) ~ 0
constexpr int CST = 32;    // cnt padding stride (ints) = 128B/counter
constexpr int AGB = (NN * 8 + 255) / 256;          // width-32 agg blocks (1563)
constexpr int C1B = (NN + 255) / 256;              // width-1 agg blocks (196)
constexpr int PREPB = (NN * 32 + 64 + 255) / 256;  // prep_all main blocks
constexpr int W34XB = 17;                          // extra blocks: w34 (4096) + v1 (32)
constexpr int W234XB = 13;                         // extra blocks: W234 (3072) + v2 (32)
constexpr int PLB = 512;                           // place blocks (single pass)

typedef unsigned short u16;
typedef int iv4 __attribute__((ext_vector_type(4)));

__device__ __forceinline__ uint2 f4_to_h4(float4 v) {
    union { unsigned u; __half2 h; } a, b;
    a.h = __float22half2_rn(make_float2(v.x, v.y));
    b.h = __float22half2_rn(make_float2(v.z, v.w));
    return make_uint2(a.u, b.u);
}
// uint4 (8 fp16) -> two float4
__device__ __forceinline__ void h8_to_f8(uint4 g, float4& lo, float4& hi) {
    union { unsigned u; __half2 h; } t;
    float2 f;
    t.u = g.x; f = __half22float2(t.h); lo.x = f.x; lo.y = f.y;
    t.u = g.y; f = __half22float2(t.h); lo.z = f.x; lo.w = f.y;
    t.u = g.z; f = __half22float2(t.h); hi.x = f.x; hi.y = f.y;
    t.u = g.w; f = __half22float2(t.h); hi.z = f.x; hi.w = f.y;
}
__device__ __forceinline__ float4 f4add(float4 a, float4 b) {
    return make_float4(a.x + b.x, a.y + b.y, a.z + b.z, a.w + b.w);
}

// Single-pass ELL build: grid-stride over int4 edge quads; every edge is
// processed exactly once (12.8 MB total edge reads). Atomics from all XCDs;
// cnt padded 1 counter/128B line.
__global__ void place_x_kernel(const int* __restrict__ row, const int* __restrict__ col,
                               int* __restrict__ cnt, u16* __restrict__ ell, int E) {
    const int n4 = E >> 2;
    const iv4* cv = (const iv4*)col;
    const iv4* rv = (const iv4*)row;
#define PLACE1(cc, rr) {                                                        \
        const int c_ = (cc);                                                    \
        if ((unsigned)c_ < (unsigned)NN) {                                      \
            const int r_ = (rr);                                                \
            if ((unsigned)r_ < (unsigned)NN) {                                  \
                const int pos = atomicAdd(&cnt[(size_t)c_ * CST], 1);           \
                if (pos < CAP) ell[c_ * CAP + pos] = (u16)r_;                   \
            }                                                                   \
        }                                                                       \
    }
    for (int i = blockIdx.x * blockDim.x + threadIdx.x; i < n4;
         i += gridDim.x * blockDim.x) {
        const iv4 c4 = cv[i];
        const iv4 r4 = rv[i];
        PLACE1(c4.x, r4.x);
        PLACE1(c4.y, r4.y);
        PLACE1(c4.z, r4.z);
        PLACE1(c4.w, r4.w);
    }
    if (blockIdx.x == 0) {              // tail for E % 4 != 0 (not hit at E=800000)
        for (int e = (n4 << 2) + threadIdx.x; e < E; e += 256) {
            const int c = col[e];
            if ((unsigned)c >= (unsigned)NN) continue;
            const int r = row[e];
            if ((unsigned)r >= (unsigned)NN) continue;
            const int pos = atomicAdd(&cnt[(size_t)c * CST], 1);
            if (pos < CAP) ell[c * CAP + pos] = (u16)r;
        }
    }
#undef PLACE1
}

// Main blocks: dis, compact mq (quad count), ELL pad-to-8 with sentinel,
// x pad+prescale, zero rows (incl. fp16 sentinel rows of Ha/Hb).
// Extra blocks: W34 = W3@W4 + v1 = b3@W4.
__global__ void prep_all_kernel(const int* __restrict__ cnt, u16* __restrict__ ell,
                                const float* __restrict__ x, float* __restrict__ dis,
                                u16* __restrict__ mq,
                                float* __restrict__ Ba, float* __restrict__ Bb,
                                unsigned* __restrict__ Ha, unsigned* __restrict__ Hb,
                                float* __restrict__ c1d,
                                const float* __restrict__ W3, const float* __restrict__ W4,
                                const float* __restrict__ b3,
                                float* __restrict__ W34, float* __restrict__ v1) {
    if (blockIdx.x >= PREPB) {
        const int wid = (blockIdx.x - PREPB) * 256 + threadIdx.x;
        if (wid < 4096) {                       // W34[r][j], lanes share r -> W3 scalarizes
            const int r = wid >> 5, j = wid & 31;
            float a = 0.f;
#pragma unroll 8
            for (int k = 0; k < 64; ++k) a = fmaf(W3[r * 64 + k], W4[k * 32 + j], a);
            W34[wid] = a;
        } else if (wid < 4128) {
            const int j = wid - 4096;
            float a = 0.f;
#pragma unroll 8
            for (int k = 0; k < 64; ++k) a = fmaf(b3[k], W4[k * 32 + j], a);
            v1[j] = a;
        }
        return;
    }
    const int idx = blockIdx.x * blockDim.x + threadIdx.x;
    if (idx < NN * 32) {
        const int n = idx >> 5, f = idx & 31;
        int m = cnt[(size_t)n * CST]; if (m > CAP) m = CAP;
        const float d = rsqrtf((float)m + 1.0f);     // +1 = self loop
        Ba[idx] = (f < 29) ? x[n * 29 + f] * d : 0.f;
        if (f == 31) dis[n] = d;
        if (f == 30) {                               // pad list to multiple of 8
            int mp = (m + 7) & ~7; if (mp > CAP) mp = CAP;
            for (int k = m; k < mp; ++k) ell[n * CAP + k] = (u16)NN;
        }
        if (f == 29) mq[n] = (u16)((m + 7) >> 3);    // compact quad count
    } else {
        const int i = idx - NN * 32;
        if (i < 32) { Ba[NN * 32 + i] = 0.f; Bb[NN * 32 + i] = 0.f; }
        if (i < 16) { Ha[NN * 16 + i] = 0u; Hb[NN * 16 + i] = 0u; }  // fp16 sentinels
        if (i == 32) dis[NN] = 0.f;
        else if (i == 33) c1d[NN] = 0.f;
    }
}

// FP32 width-32 pull (pre-agg only): out = dis*acc. 8 lanes/node, float4.
__device__ __forceinline__ void agg32_body(const float* __restrict__ hs,
                                           const u16* __restrict__ mq,
                                           const u16* __restrict__ ell,
                                           const float* __restrict__ dis,
                                           float* __restrict__ out) {
    const int idx = blockIdx.x * blockDim.x + threadIdx.x;
    if (idx >= NN * 8) return;
    const int n = idx >> 3, c = idx & 7;
    const float4* hpc = (const float4*)hs + c;
    float4 acc = hpc[n * 8];                    // self-loop term
    const int m8 = mq[n];
    const int4* ip = (const int4*)(ell + (size_t)n * CAP);
    int t = 0;
    for (; t + 2 <= m8; t += 2) {               // 16 gathers in flight
        const int4 sA = ip[t], sB = ip[t + 1];
        const unsigned ax = (unsigned)sA.x, ay = (unsigned)sA.y;
        const unsigned az = (unsigned)sA.z, aw = (unsigned)sA.w;
        const unsigned bx = (unsigned)sB.x, by = (unsigned)sB.y;
        const unsigned bz = (unsigned)sB.z, bw = (unsigned)sB.w;
        const float4 g0 = hpc[(ax & 0xFFFFu) * 8], g1 = hpc[(ax >> 16) * 8];
        const float4 g2 = hpc[(ay & 0xFFFFu) * 8], g3 = hpc[(ay >> 16) * 8];
        const float4 g4 = hpc[(az & 0xFFFFu) * 8], g5 = hpc[(az >> 16) * 8];
        const float4 g6 = hpc[(aw & 0xFFFFu) * 8], g7 = hpc[(aw >> 16) * 8];
        const float4 h0 = hpc[(bx & 0xFFFFu) * 8], h1 = hpc[(bx >> 16) * 8];
        const float4 h2 = hpc[(by & 0xFFFFu) * 8], h3 = hpc[(by >> 16) * 8];
        const float4 h4 = hpc[(bz & 0xFFFFu) * 8], h5 = hpc[(bz >> 16) * 8];
        const float4 h6 = hpc[(bw & 0xFFFFu) * 8], h7 = hpc[(bw >> 16) * 8];
        acc.x += (((g0.x + g1.x) + (g2.x + g3.x)) + ((g4.x + g5.x) + (g6.x + g7.x)))
               + (((h0.x + h1.x) + (h2.x + h3.x)) + ((h4.x + h5.x) + (h6.x + h7.x)));
        acc.y += (((g0.y + g1.y) + (g2.y + g3.y)) + ((g4.y + g5.y) + (g6.y + g7.y)))
               + (((h0.y + h1.y) + (h2.y + h3.y)) + ((h4.y + h5.y) + (h6.y + h7.y)));
        acc.z += (((g0.z + g1.z) + (g2.z + g3.z)) + ((g4.z + g5.z) + (g6.z + g7.z)))
               + (((h0.z + h1.z) + (h2.z + h3.z)) + ((h4.z + h5.z) + (h6.z + h7.z)));
        acc.w += (((g0.w + g1.w) + (g2.w + g3.w)) + ((g4.w + g5.w) + (g6.w + g7.w)))
               + (((h0.w + h1.w) + (h2.w + h3.w)) + ((h4.w + h5.w) + (h6.w + h7.w)));
    }
    if (t < m8) {
        const int4 s = ip[t];
        const unsigned ux = (unsigned)s.x, uy = (unsigned)s.y;
        const unsigned uz = (unsigned)s.z, uw = (unsigned)s.w;
        const float4 g0 = hpc[(ux & 0xFFFFu) * 8], g1 = hpc[(ux >> 16) * 8];
        const float4 g2 = hpc[(uy & 0xFFFFu) * 8], g3 = hpc[(uy >> 16) * 8];
        const float4 g4 = hpc[(uz & 0xFFFFu) * 8], g5 = hpc[(uz >> 16) * 8];
        const float4 g6 = hpc[(uw & 0xFFFFu) * 8], g7 = hpc[(uw >> 16) * 8];
        acc.x += ((g0.x + g1.x) + (g2.x + g3.x)) + ((g4.x + g5.x) + (g6.x + g7.x));
        acc.y += ((g0.y + g1.y) + (g2.y + g3.y)) + ((g4.y + g5.y) + (g6.y + g7.y));
        acc.z += ((g0.z + g1.z) + (g2.z + g3.z)) + ((g4.z + g5.z) + (g6.z + g7.z));
        acc.w += ((g0.w + g1.w) + (g2.w + g3.w)) + ((g4.w + g5.w) + (g6.w + g7.w));
    }
    const float d = dis[n];
    float4 r;
    r.x = acc.x * d; r.y = acc.y * d; r.z = acc.z * d; r.w = acc.w * d;
    ((float4*)out)[idx] = r;
}

// FP16 16B-lane hop pull: lane c of node n handles chunk q=c&3 (8 fp16
// feats) and edge-parity h=c>>2. Parity partials merged via shfl_xor(4).
// fp32 accum. MODE 1: out fp16, (acc)*d^2. MODE 2: out fp32 + rank-1 fixups.
template<int MODE>
__device__ __forceinline__ void agg32h_body(const uint4* __restrict__ hh,
                                            const u16* __restrict__ mq,
                                            const u16* __restrict__ ell,
                                            const float* __restrict__ dis,
                                            const float* __restrict__ c1,
                                            const float* __restrict__ c2,
                                            const float* __restrict__ v1,
                                            const float* __restrict__ v2,
                                            const float* __restrict__ bv,
                                            void* __restrict__ out) {
    const int idx = blockIdx.x * blockDim.x + threadIdx.x;
    if (idx >= NN * 8) return;
    const int n = idx >> 3, c = idx & 7;
    const int q = c & 3;                   // 16B chunk within 64B row
    const int h = c >> 2;                  // edge parity
    const uint4* hp = hh + q;              // + row*4 indexes chunk q of a row
    float4 aL, aH;
    {
        float4 sl, sh;
        h8_to_f8(hp[(size_t)n * 4], sl, sh);
        const float m0 = h ? 0.f : 1.f;
        aL = make_float4(sl.x * m0, sl.y * m0, sl.z * m0, sl.w * m0);
        aH = make_float4(sh.x * m0, sh.y * m0, sh.z * m0, sh.w * m0);
    }
    const int m8 = mq[n];
    const int4* ip = (const int4*)(ell + (size_t)n * CAP);
    int t = 0;
    for (; t + 2 <= m8; t += 2) {           // 8 x 16B gathers in flight (16 edges)
        const int4 sA = ip[t], sB = ip[t + 1];
        const unsigned a0 = (unsigned)sA.x, a1 = (unsigned)sA.y;
        const unsigned a2 = (unsigned)sA.z, a3 = (unsigned)sA.w;
        const unsigned b0 = (unsigned)sB.x, b1 = (unsigned)sB.y;
        const unsigned b2 = (unsigned)sB.z, b3 = (unsigned)sB.w;
        const unsigned i0 = h ? (a0 >> 16) : (a0 & 0xFFFFu);
        const unsigned i1 = h ? (a1 >> 16) : (a1 & 0xFFFFu);
        const unsigned i2 = h ? (a2 >> 16) : (a2 & 0xFFFFu);
        const unsigned i3 = h ? (a3 >> 16) : (a3 & 0xFFFFu);
        const unsigned i4 = h ? (b0 >> 16) : (b0 & 0xFFFFu);
        const unsigned i5 = h ? (b1 >> 16) : (b1 & 0xFFFFu);
        const unsigned i6 = h ? (b2 >> 16) : (b2 & 0xFFFFu);
        const unsigned i7 = h ? (b3 >> 16) : (b3 & 0xFFFFu);
        const uint4 g0 = hp[(size_t)i0 * 4], g1 = hp[(size_t)i1 * 4];
        const uint4 g2 = hp[(size_t)i2 * 4], g3 = hp[(size_t)i3 * 4];
        const uint4 g4 = hp[(size_t)i4 * 4], g5 = hp[(size_t)i5 * 4];
        const uint4 g6 = hp[(size_t)i6 * 4], g7 = hp[(size_t)i7 * 4];
        float4 l0, h0, l1, h1, l2, h2, l3, h3, l4, h4, l5, h5, l6, h6, l7, h7;
        h8_to_f8(g0, l0, h0); h8_to_f8(g1, l1, h1);
        h8_to_f8(g2, l2, h2); h8_to_f8(g3, l3, h3);
        h8_to_f8(g4, l4, h4); h8_to_f8(g5, l5, h5);
        h8_to_f8(g6, l6, h6); h8_to_f8(g7, l7, h7);
        aL = f4add(aL, f4add(f4add(f4add(l0, l1), f4add(l2, l3)),
                             f4add(f4add(l4, l5), f4add(l6, l7))));
        aH = f4add(aH, f4add(f4add(f4add(h0, h1), f4add(h2, h3)),
                             f4add(f4add(h4, h5), f4add(h6, h7))));
    }
    if (t < m8) {                           // tail quad: 4 gathers (8 edges)
        const int4 s = ip[t];
        const unsigned w0 = (unsigned)s.x, w1 = (unsigned)s.y;
        const unsigned w2 = (unsigned)s.z, w3 = (unsigned)s.w;
        const unsigned i0 = h ? (w0 >> 16) : (w0 & 0xFFFFu);
        const unsigned i1 = h ? (w1 >> 16) : (w1 & 0xFFFFu);
        const unsigned i2 = h ? (w2 >> 16) : (w2 & 0xFFFFu);
        const unsigned i3 = h ? (w3 >> 16) : (w3 & 0xFFFFu);
        const uint4 g0 = hp[(size_t)i0 * 4], g1 = hp[(size_t)i1 * 4];
        const uint4 g2 = hp[(size_t)i2 * 4], g3 = hp[(size_t)i3 * 4];
        float4 l0, h0, l1, h1, l2, h2, l3, h3;
        h8_to_f8(g0, l0, h0); h8_to_f8(g1, l1, h1);
        h8_to_f8(g2, l2, h2); h8_to_f8(g3, l3, h3);
        aL = f4add(aL, f4add(f4add(l0, l1), f4add(l2, l3)));
        aH = f4add(aH, f4add(f4add(h0, h1), f4add(h2, h3)));
    }
    // merge edge-parity partials: lanes c and c^4 hold same chunk q
    aL.x += __shfl_xor(aL.x, 4); aL.y += __shfl_xor(aL.y, 4);
    aL.z += __shfl_xor(aL.z, 4); aL.w += __shfl_xor(aL.w, 4);
    aH.x += __shfl_xor(aH.x, 4); aH.y += __shfl_xor(aH.y, 4);
    aH.z += __shfl_xor(aH.z, 4); aH.w += __shfl_xor(aH.w, 4);
    const float d = dis[n];
    if (MODE == 1) {
        if (c < 4) {                         // lanes 0-3 store chunks 0-3 (fp16)
            const float d2 = d * d;
            float4 rl = make_float4(aL.x * d2, aL.y * d2, aL.z * d2, aL.w * d2);
            float4 rh = make_float4(aH.x * d2, aH.y * d2, aH.z * d2, aH.w * d2);
            const uint2 pl = f4_to_h4(rl), ph = f4_to_h4(rh);
            uint4 o; o.x = pl.x; o.y = pl.y; o.z = ph.x; o.w = ph.y;
            ((uint4*)out)[(size_t)n * 4 + q] = o;
        }
    } else {
        // redistribute: lane c wants feats 4c..4c+3 = chunk c>>1, half c&1
        const int lane = threadIdx.x & 63;
        const int src = (lane & ~7) | (c >> 1);
        const float s0 = __shfl(aL.x, src), s1 = __shfl(aL.y, src);
        const float s2 = __shfl(aL.z, src), s3 = __shfl(aL.w, src);
        const float s4 = __shfl(aH.x, src), s5 = __shfl(aH.y, src);
        const float s6 = __shfl(aH.z, src), s7 = __shfl(aH.w, src);
        const float4 acc = (c & 1) ? make_float4(s4, s5, s6, s7)
                                   : make_float4(s0, s1, s2, s3);
        const float a1 = c1[n], a2 = c2[n];
        const float4 w1 = ((const float4*)v1)[c];
        const float4 w2 = ((const float4*)v2)[c];
        const float4 bb = ((const float4*)bv)[c];
        float4 r;
        r.x = fmaf(acc.x, d, fmaf(a1, w1.x, fmaf(a2, w2.x, bb.x)));
        r.y = fmaf(acc.y, d, fmaf(a1, w1.y, fmaf(a2, w2.y, bb.y)));
        r.z = fmaf(acc.z, d, fmaf(a1, w1.z, fmaf(a2, w2.z, bb.z)));
        r.w = fmaf(acc.w, d, fmaf(a1, w1.w, fmaf(a2, w2.w, bb.w)));
        ((float4*)out)[idx] = r;
    }
}

// Width-1 pull: out[n] = dis[n]*(in[n] + sum in[src]); optional outd = out*dis.
__device__ __forceinline__ void agg1_body(const float* __restrict__ in,
                                          const u16* __restrict__ mq,
                                          const u16* __restrict__ ell,
                                          const float* __restrict__ dis,
                                          float* __restrict__ out,
                                          float* __restrict__ outd, int blk0) {
    const int n = (blockIdx.x - blk0) * 256 + threadIdx.x;
    if (n >= NN) return;
    float acc = in[n];
    const int m8 = mq[n];
    const iv4* ip = (const iv4*)(ell + (size_t)n * CAP);
    for (int t = 0; t < m8; ++t) {
        const iv4 s = ip[t];
        const unsigned ux = (unsigned)s.x, uy = (unsigned)s.y;
        const unsigned uz = (unsigned)s.z, uw = (unsigned)s.w;
        acc += ((in[ux & 0xFFFFu] + in[ux >> 16]) + (in[uy & 0xFFFFu] + in[uy >> 16]))
             + ((in[uz & 0xFFFFu] + in[uz >> 16]) + (in[uw & 0xFFFFu] + in[uw >> 16]));
    }
    const float r = dis[n] * acc;
    out[n] = r;
    if (outd) outd[n] = r * dis[n];
}

// Layer-1 pre-agg (fp32) + folded c1 = A.1 + folded W234 = W2@W34, v2 = b2@W34.
__global__ void agg_pre_kernel(const float* __restrict__ Ba, const u16* __restrict__ mq,
                               const u16* __restrict__ ell, const float* __restrict__ dis,
                               float* __restrict__ Bb, float* __restrict__ c1,
                               float* __restrict__ c1d,
                               const float* __restrict__ W2, const float* __restrict__ b2,
                               const float* __restrict__ W34, float* __restrict__ W234,
                               float* __restrict__ v2) {
    if (blockIdx.x < AGB) {
        agg32_body(Ba, mq, ell, dis, Bb);
    } else if (blockIdx.x < AGB + C1B) {
        agg1_body(dis, mq, ell, dis, c1, c1d, AGB);
    } else {
        const int wid = (blockIdx.x - AGB - C1B) * 256 + threadIdx.x;
        if (wid < 3072) {                       // W234[r][j], lanes share r
            const int r = wid >> 5, j = wid & 31;
            float a = 0.f;
#pragma unroll 8
            for (int k = 0; k < 128; ++k) a = fmaf(W2[r * 128 + k], W34[k * 32 + j], a);
            W234[wid] = a;
        } else if (wid < 3104) {
            const int j = wid - 3072;
            float a = 0.f;
#pragma unroll 8
            for (int k = 0; k < 128; ++k) a = fmaf(b2[k], W34[k * 32 + j], a);
            v2[j] = a;
        }
    }
}

// Hop 1 (half->half) + folded c2 = A.(c1*dis).
__global__ void agg_hop1_kernel(const uint4* __restrict__ Ha, const u16* __restrict__ mq,
                                const u16* __restrict__ ell, const float* __restrict__ dis,
                                uint4* __restrict__ Hb, const float* __restrict__ c1d,
                                float* __restrict__ c2) {
    if (blockIdx.x < AGB)
        agg32h_body<1>(Ha, mq, ell, dis, nullptr, nullptr, nullptr, nullptr, nullptr, Hb);
    else
        agg1_body(c1d, mq, ell, dis, c2, nullptr, AGB);
}

// Hop 2 (half->half).
__global__ void agg_hop2_kernel(const uint4* __restrict__ Hb, const u16* __restrict__ mq,
                                const u16* __restrict__ ell, const float* __restrict__ dis,
                                uint4* __restrict__ Ha) {
    agg32h_body<1>(Hb, mq, ell, dis, nullptr, nullptr, nullptr, nullptr, nullptr, Ha);
}

// Hop 3 (half->fp32) + rank-1 fixups.
__global__ void agg_hop3_kernel(const uint4* __restrict__ Ha, const u16* __restrict__ mq,
                                const u16* __restrict__ ell, const float* __restrict__ dis,
                                const float* __restrict__ c1, const float* __restrict__ c2,
                                const float* __restrict__ v1, const float* __restrict__ v2,
                                const float* __restrict__ bv, float* __restrict__ out) {
    agg32h_body<2>(Ha, mq, ell, dis, c1, c2, v1, v2, bv, out);
}

// Fused dense path: h1d = relu(Xa@W1+b1)*dis (LDS), g = h1d@W234 -> G (fp16).
// 8 accs/thread max; __launch_bounds__(192,2) -> no spill (r13-proven).
__global__ void __launch_bounds__(192, 2)
gemm_fused_kernel(const float* __restrict__ X, const float* __restrict__ W1,
                  const float* __restrict__ b1, const float* __restrict__ dis,
                  const float* __restrict__ W234, uint2* __restrict__ G) {
    constexpr int NPB = 16, RSX = 36, RSH = 104;
    __shared__ float xs[NPB * RSX];
    __shared__ float hsm[NPB * RSH];
    const int tid = threadIdx.x;
    const int n0  = blockIdx.x * NPB;

    const float4* Xv = (const float4*)(X + (size_t)n0 * 32);
    for (int i = tid; i < NPB * 8; i += 192) {
        const int nl = i >> 3, r = i & 7;
        float4 v = make_float4(0.f, 0.f, 0.f, 0.f);
        if (n0 + nl < NN) v = Xv[nl * 8 + r];
        *(float4*)(xs + nl * RSX + r * 4) = v;
    }
    __syncthreads();

    {   // phase A: 29 -> 96, relu(+b1)*dis, result to LDS
        const int cg = tid % 24, g = tid / 24;
        const float* x0 = xs + (2 * g) * RSX;
        const float* x1 = x0 + RSX;
        const float4* Wv = (const float4*)W1;
        float4 a0 = make_float4(0.f, 0.f, 0.f, 0.f);
        float4 a1 = make_float4(0.f, 0.f, 0.f, 0.f);
#pragma unroll
        for (int k = 0; k < 29; ++k) {
            const float4 w = Wv[k * 24 + cg];
            const float v0 = x0[k], v1 = x1[k];
            a0.x = fmaf(v0, w.x, a0.x); a0.y = fmaf(v0, w.y, a0.y);
            a0.z = fmaf(v0, w.z, a0.z); a0.w = fmaf(v0, w.w, a0.w);
            a1.x = fmaf(v1, w.x, a1.x); a1.y = fmaf(v1, w.y, a1.y);
            a1.z = fmaf(v1, w.z, a1.z); a1.w = fmaf(v1, w.w, a1.w);
        }
        const float4 bb = ((const float4*)b1)[cg];
#pragma unroll
        for (int h = 0; h < 2; ++h) {
            const int nl = 2 * g + h, node = n0 + nl;
            const float d = (node < NN) ? dis[node] : 0.f;
            const float4 a = h ? a1 : a0;
            float4 r;
            r.x = fmaxf(a.x + bb.x, 0.f) * d; r.y = fmaxf(a.y + bb.y, 0.f) * d;
            r.z = fmaxf(a.z + bb.z, 0.f) * d; r.w = fmaxf(a.w + bb.w, 0.f) * d;
            *(float4*)(hsm + nl * RSH + cg * 4) = r;
        }
    }
    __syncthreads();

    if (tid < 128) {  // phase B: 96 -> 32 raw, store fp16
        const int nl = tid >> 3, cg = tid & 7;
        const float* hr = hsm + nl * RSH;
        const float4* Wv = (const float4*)W234;
        float4 a = make_float4(0.f, 0.f, 0.f, 0.f);
#pragma unroll 8
        for (int k = 0; k < 96; ++k) {
            const float4 w = Wv[k * 8 + cg];
            const float v = hr[k];
            a.x = fmaf(v, w.x, a.x); a.y = fmaf(v, w.y, a.y);
            a.z = fmaf(v, w.z, a.z); a.w = fmaf(v, w.w, a.w);
        }
        const int node = n0 + nl;
        if (node < NN) G[(size_t)node * 8 + cg] = f4_to_h4(a);
    }
}

extern "C" void kernel_launch(void* const* d_in, const int* in_sizes, int n_in,
                              void* d_out, int out_size, void* d_ws, size_t ws_size,
                              hipStream_t stream) {
    const float* x  = (const float*)d_in[0];
    const int*   ei = (const int*)d_in[1];           // int32 (harness converts)
    const float* W1 = (const float*)d_in[2]; const float* b1 = (const float*)d_in[3];
    const float* W2 = (const float*)d_in[4]; const float* b2 = (const float*)d_in[5];
    const float* W3 = (const float*)d_in[6]; const float* b3 = (const float*)d_in[7];
    const float* W4 = (const float*)d_in[8]; const float* b4p = (const float*)d_in[9];
    float* outp = (float*)d_out;

    const int E = in_sizes[1] / 2;          // 800000
    const int* row = ei;
    const int* col = ei + E;

    // Workspace (4B elems, 64B-aligned sections), ~33 MB:
    int*   cnt  = (int*)d_ws;                       // 50048*32 ints (padded, 6.4 MB)
    float* dis  = (float*)(cnt + 50048 * CST);      // 50064 floats (uses [NN])
    u16*   ell  = (u16*)(dis + 50064);              // NN*CAP u16 = 1,600,000 ints
    u16*   mq   = (u16*)((int*)ell + 1600000);      // 50048 u16 = 25024 ints
    float* c1   = (float*)((int*)mq + 25024);       // 50064
    float* c1d  = c1 + 50064;                       // 50064 (uses [NN])
    float* c2   = c1d + 50064;                      // 50064
    float* W34  = c2 + 50064;                       // 4096
    float* W234 = W34 + 4096;                       // 3072
    float* v1   = W234 + 3072;                      // 32
    float* v2   = v1 + 32;                          // 32
    float* Ba   = v2 + 32;                          // (NN+1)*32 = 1600064
    float* Bb   = Ba + 1600064;                     // 1600064
    unsigned* Ha = (unsigned*)(Bb + 1600064);       // (NN+1)*16 uints (fp16 rows)
    unsigned* Hb = Ha + 800032;                     // (NN+1)*16 uints

    // 1. zero padded counters (6.4 MB)
    hipMemsetAsync(cnt, 0, (size_t)50048 * CST * sizeof(int), stream);
    // 2. build ELL, single pass (512 blocks, int4 edge loads, grid-stride)
    place_x_kernel<<<PLB, 256, 0, stream>>>(row, col, cnt, ell, E);
    // 3. dis + mq + pad + xpad + sentinels (incl. fp16 rows); extra: W34 + v1
    prep_all_kernel<<<PREPB + W34XB, 256, 0, stream>>>(cnt, ell, x, dis, mq, Ba, Bb,
                                                       Ha, Hb, c1d, W3, W4, b3, W34, v1);
    // 4. layer-1 pre-agg fp32 (Ba->Bb) + folded c1; extra blocks: W234 + v2
    agg_pre_kernel<<<AGB + C1B + W234XB, 256, 0, stream>>>(Ba, mq, ell, dis, Bb, c1, c1d,
                                                           W2, b2, W34, W234, v2);
    // 5. fused dense: Ha(fp16) = relu(Bb@W1+b1)*dis @ W234
    gemm_fused_kernel<<<(NN + 15) / 16, 192, 0, stream>>>(Bb, W1, b1, dis, W234,
                                                          (uint2*)Ha);
    // 6. hop 1 (Ha->Hb, 16B-lane fp16 gathers) + folded c2
    agg_hop1_kernel<<<AGB + C1B, 256, 0, stream>>>((const uint4*)Ha, mq, ell, dis,
                                                   (uint4*)Hb, c1d, c2);
    // 7. hop 2 (Hb->Ha)
    agg_hop2_kernel<<<AGB, 256, 0, stream>>>((const uint4*)Hb, mq, ell, dis, (uint4*)Ha);
    // 8. hop 3 + rank-1 fixups (Ha->out, fp32)
    agg_hop3_kernel<<<AGB, 256, 0, stream>>>((const uint4*)Ha, mq, ell, dis,
                                             c1, c2, v1, v2, b4p, outp);
}

// Round 10
// 207.162 us; speedup vs baseline: 1.1235x; 1.1235x over previous
//
#include <hip/hip_runtime.h>
#include <hip/hip_fp16.h>

// GCN 4-layer: 29->96->128->64->32, N=50000, E=800000 (+self loops).
// Round 29 = (a) REVERT place_x to r27's 8-group XCD-affine build — r28
// proved atomic XCD-locality is real (single-pass all-XCD atomics: place_x
// 44 -> 70 us, +22 total, despite 8x fewer edge reads) — and (b) make the
// pre-agg gather FP16 like the hops (r24: -11 us over 3 hops): x-hat stored
// as fp16 Xh, gathered 16B/lane with edge-parity split; output Bb stays
// fp32 (gemm reads it linearly). fp32 accumulation everywhere.
// Structure: collapsed layers 2-4 (out = A^3(h1 W234)+c2 v2+c1 v1+b4),
// u16 ELL + 8-index int4 gathers, fp16 gather buffers (Xh/Ha/Hb),
// padded cnt (CST=32, r27-verified neutral), weight collapse riding
// prep/agg_pre. 8 dispatches. No cooperative launches.
// NOTE: harness delivers integer inputs as int32.

constexpr int NN  = 50000;
constexpr int CAP = 64;    // max in-degree; Poisson(16) over 50K => P(>=64) ~ 0
constexpr int CST = 32;    // cnt padding stride (ints) = 128B/counter
constexpr int AGB = (NN * 8 + 255) / 256;          // width-32 agg blocks (1563)
constexpr int C1B = (NN + 255) / 256;              // width-1 agg blocks (196)
constexpr int PREPB = (NN * 32 + 64 + 255) / 256;  // prep_all main blocks
constexpr int W34XB = 17;                          // extra blocks: w34 (4096) + v1 (32)
constexpr int W234XB = 13;                         // extra blocks: W234 (3072) + v2 (32)
constexpr int PXB = 256;                           // place blocks per XCD group

typedef unsigned short u16;
typedef int iv4 __attribute__((ext_vector_type(4)));

__device__ __forceinline__ uint2 f4_to_h4(float4 v) {
    union { unsigned u; __half2 h; } a, b;
    a.h = __float22half2_rn(make_float2(v.x, v.y));
    b.h = __float22half2_rn(make_float2(v.z, v.w));
    return make_uint2(a.u, b.u);
}
// uint4 (8 fp16) -> two float4
__device__ __forceinline__ void h8_to_f8(uint4 g, float4& lo, float4& hi) {
    union { unsigned u; __half2 h; } t;
    float2 f;
    t.u = g.x; f = __half22float2(t.h); lo.x = f.x; lo.y = f.y;
    t.u = g.y; f = __half22float2(t.h); lo.z = f.x; lo.w = f.y;
    t.u = g.z; f = __half22float2(t.h); hi.x = f.x; hi.y = f.y;
    t.u = g.w; f = __half22float2(t.h); hi.z = f.x; hi.w = f.y;
}
__device__ __forceinline__ float4 f4add(float4 a, float4 b) {
    return make_float4(a.x + b.x, a.y + b.y, a.z + b.z, a.w + b.w);
}

// XCD-affine ELL build (r27): 8 groups x 256 blocks; group g keeps dests
// with (c>>6)&7 == g -> atomics stay XCD-local (r28: violating this costs
// +26 us). int4 edge loads; cnt padded 1 counter/128B.
__global__ void place_x_kernel(const int* __restrict__ row, const int* __restrict__ col,
                               int* __restrict__ cnt, u16* __restrict__ ell, int E) {
    const int g  = blockIdx.x & 7;
    const int bi = blockIdx.x >> 3;
    const int n4 = E >> 2;
    const int slice = (n4 + PXB - 1) / PXB;
    const int i0 = bi * slice;
    int i1 = i0 + slice; if (i1 > n4) i1 = n4;
    const iv4* cv = (const iv4*)col;
    const iv4* rv = (const iv4*)row;
#define PLACE1(cc, rr) {                                                        \
        const int c_ = (cc);                                                    \
        if ((((c_ >> 6) & 7) == g) && (unsigned)c_ < (unsigned)NN) {            \
            const int r_ = (rr);                                                \
            if ((unsigned)r_ < (unsigned)NN) {                                  \
                const int pos = atomicAdd(&cnt[(size_t)c_ * CST], 1);           \
                if (pos < CAP) ell[c_ * CAP + pos] = (u16)r_;                   \
            }                                                                   \
        }                                                                       \
    }
    for (int i = i0 + threadIdx.x; i < i1; i += 256) {
        const iv4 c4 = cv[i];
        const iv4 r4 = rv[i];
        PLACE1(c4.x, r4.x);
        PLACE1(c4.y, r4.y);
        PLACE1(c4.z, r4.z);
        PLACE1(c4.w, r4.w);
    }
    if (bi == 0) {                      // tail for E % 4 != 0 (not hit at E=800000)
        for (int e = (n4 << 2) + threadIdx.x; e < E; e += 256) {
            const int c = col[e];
            if (((c >> 6) & 7) != g || (unsigned)c >= (unsigned)NN) continue;
            const int r = row[e];
            if ((unsigned)r >= (unsigned)NN) continue;
            const int pos = atomicAdd(&cnt[(size_t)c * CST], 1);
            if (pos < CAP) ell[c * CAP + pos] = (u16)r;
        }
    }
#undef PLACE1
}

// Main blocks: dis, compact mq (quad count), ELL pad-to-8 with sentinel,
// x-hat as FP16 (Xh), zero sentinel rows of Xh/Ha/Hb.
// Extra blocks: W34 = W3@W4 + v1 = b3@W4.
__global__ void prep_all_kernel(const int* __restrict__ cnt, u16* __restrict__ ell,
                                const float* __restrict__ x, float* __restrict__ dis,
                                u16* __restrict__ mq,
                                unsigned* __restrict__ Xh,
                                unsigned* __restrict__ Ha, unsigned* __restrict__ Hb,
                                float* __restrict__ c1d,
                                const float* __restrict__ W3, const float* __restrict__ W4,
                                const float* __restrict__ b3,
                                float* __restrict__ W34, float* __restrict__ v1) {
    if (blockIdx.x >= PREPB) {
        const int wid = (blockIdx.x - PREPB) * 256 + threadIdx.x;
        if (wid < 4096) {                       // W34[r][j], lanes share r -> W3 scalarizes
            const int r = wid >> 5, j = wid & 31;
            float a = 0.f;
#pragma unroll 8
            for (int k = 0; k < 64; ++k) a = fmaf(W3[r * 64 + k], W4[k * 32 + j], a);
            W34[wid] = a;
        } else if (wid < 4128) {
            const int j = wid - 4096;
            float a = 0.f;
#pragma unroll 8
            for (int k = 0; k < 64; ++k) a = fmaf(b3[k], W4[k * 32 + j], a);
            v1[j] = a;
        }
        return;
    }
    const int idx = blockIdx.x * blockDim.x + threadIdx.x;
    if (idx < NN * 32) {
        const int n = idx >> 5, f = idx & 31;
        int m = cnt[(size_t)n * CST]; if (m > CAP) m = CAP;
        const float d = rsqrtf((float)m + 1.0f);     // +1 = self loop
        const float val = (f < 29) ? x[n * 29 + f] * d : 0.f;
        ((__half*)Xh)[idx] = __float2half(val);      // fp16 x-hat
        if (f == 31) dis[n] = d;
        if (f == 30) {                               // pad list to multiple of 8
            int mp = (m + 7) & ~7; if (mp > CAP) mp = CAP;
            for (int k = m; k < mp; ++k) ell[n * CAP + k] = (u16)NN;
        }
        if (f == 29) mq[n] = (u16)((m + 7) >> 3);    // compact quad count
    } else {
        const int i = idx - NN * 32;
        if (i < 16) {                                 // fp16 sentinel rows
            Xh[NN * 16 + i] = 0u; Ha[NN * 16 + i] = 0u; Hb[NN * 16 + i] = 0u;
        }
        if (i == 32) dis[NN] = 0.f;
        else if (i == 33) c1d[NN] = 0.f;
    }
}

// FP16 16B-lane pull: lane c of node n handles chunk q=c&3 (8 fp16 feats)
// and edge-parity h=c>>2. Parity partials merged via shfl_xor(4). fp32
// accum. MODE 0: out fp32, acc*d (pre-agg -> gemm input). MODE 1: out fp16,
// acc*d^2 (chain hops). MODE 2: out fp32 + rank-1 fixups (final).
template<int MODE>
__device__ __forceinline__ void agg32h_body(const uint4* __restrict__ hh,
                                            const u16* __restrict__ mq,
                                            const u16* __restrict__ ell,
                                            const float* __restrict__ dis,
                                            const float* __restrict__ c1,
                                            const float* __restrict__ c2,
                                            const float* __restrict__ v1,
                                            const float* __restrict__ v2,
                                            const float* __restrict__ bv,
                                            void* __restrict__ out) {
    const int idx = blockIdx.x * blockDim.x + threadIdx.x;
    if (idx >= NN * 8) return;
    const int n = idx >> 3, c = idx & 7;
    const int q = c & 3;                   // 16B chunk within 64B row
    const int h = c >> 2;                  // edge parity
    const uint4* hp = hh + q;              // + row*4 indexes chunk q of a row
    float4 aL, aH;
    {
        float4 sl, sh;
        h8_to_f8(hp[(size_t)n * 4], sl, sh);
        const float m0 = h ? 0.f : 1.f;
        aL = make_float4(sl.x * m0, sl.y * m0, sl.z * m0, sl.w * m0);
        aH = make_float4(sh.x * m0, sh.y * m0, sh.z * m0, sh.w * m0);
    }
    const int m8 = mq[n];
    const int4* ip = (const int4*)(ell + (size_t)n * CAP);
    int t = 0;
    for (; t + 2 <= m8; t += 2) {           // 8 x 16B gathers in flight (16 edges)
        const int4 sA = ip[t], sB = ip[t + 1];
        const unsigned a0 = (unsigned)sA.x, a1 = (unsigned)sA.y;
        const unsigned a2 = (unsigned)sA.z, a3 = (unsigned)sA.w;
        const unsigned b0 = (unsigned)sB.x, b1 = (unsigned)sB.y;
        const unsigned b2 = (unsigned)sB.z, b3 = (unsigned)sB.w;
        const unsigned i0 = h ? (a0 >> 16) : (a0 & 0xFFFFu);
        const unsigned i1 = h ? (a1 >> 16) : (a1 & 0xFFFFu);
        const unsigned i2 = h ? (a2 >> 16) : (a2 & 0xFFFFu);
        const unsigned i3 = h ? (a3 >> 16) : (a3 & 0xFFFFu);
        const unsigned i4 = h ? (b0 >> 16) : (b0 & 0xFFFFu);
        const unsigned i5 = h ? (b1 >> 16) : (b1 & 0xFFFFu);
        const unsigned i6 = h ? (b2 >> 16) : (b2 & 0xFFFFu);
        const unsigned i7 = h ? (b3 >> 16) : (b3 & 0xFFFFu);
        const uint4 g0 = hp[(size_t)i0 * 4], g1 = hp[(size_t)i1 * 4];
        const uint4 g2 = hp[(size_t)i2 * 4], g3 = hp[(size_t)i3 * 4];
        const uint4 g4 = hp[(size_t)i4 * 4], g5 = hp[(size_t)i5 * 4];
        const uint4 g6 = hp[(size_t)i6 * 4], g7 = hp[(size_t)i7 * 4];
        float4 l0, h0, l1, h1, l2, h2, l3, h3, l4, h4, l5, h5, l6, h6, l7, h7;
        h8_to_f8(g0, l0, h0); h8_to_f8(g1, l1, h1);
        h8_to_f8(g2, l2, h2); h8_to_f8(g3, l3, h3);
        h8_to_f8(g4, l4, h4); h8_to_f8(g5, l5, h5);
        h8_to_f8(g6, l6, h6); h8_to_f8(g7, l7, h7);
        aL = f4add(aL, f4add(f4add(f4add(l0, l1), f4add(l2, l3)),
                             f4add(f4add(l4, l5), f4add(l6, l7))));
        aH = f4add(aH, f4add(f4add(f4add(h0, h1), f4add(h2, h3)),
                             f4add(f4add(h4, h5), f4add(h6, h7))));
    }
    if (t < m8) {                           // tail quad: 4 gathers (8 edges)
        const int4 s = ip[t];
        const unsigned w0 = (unsigned)s.x, w1 = (unsigned)s.y;
        const unsigned w2 = (unsigned)s.z, w3 = (unsigned)s.w;
        const unsigned i0 = h ? (w0 >> 16) : (w0 & 0xFFFFu);
        const unsigned i1 = h ? (w1 >> 16) : (w1 & 0xFFFFu);
        const unsigned i2 = h ? (w2 >> 16) : (w2 & 0xFFFFu);
        const unsigned i3 = h ? (w3 >> 16) : (w3 & 0xFFFFu);
        const uint4 g0 = hp[(size_t)i0 * 4], g1 = hp[(size_t)i1 * 4];
        const uint4 g2 = hp[(size_t)i2 * 4], g3 = hp[(size_t)i3 * 4];
        float4 l0, h0, l1, h1, l2, h2, l3, h3;
        h8_to_f8(g0, l0, h0); h8_to_f8(g1, l1, h1);
        h8_to_f8(g2, l2, h2); h8_to_f8(g3, l3, h3);
        aL = f4add(aL, f4add(f4add(l0, l1), f4add(l2, l3)));
        aH = f4add(aH, f4add(f4add(h0, h1), f4add(h2, h3)));
    }
    // merge edge-parity partials: lanes c and c^4 hold same chunk q
    aL.x += __shfl_xor(aL.x, 4); aL.y += __shfl_xor(aL.y, 4);
    aL.z += __shfl_xor(aL.z, 4); aL.w += __shfl_xor(aL.w, 4);
    aH.x += __shfl_xor(aH.x, 4); aH.y += __shfl_xor(aH.y, 4);
    aH.z += __shfl_xor(aH.z, 4); aH.w += __shfl_xor(aH.w, 4);
    const float d = dis[n];
    if (MODE == 1) {
        if (c < 4) {                         // lanes 0-3 store chunks 0-3 (fp16)
            const float d2 = d * d;
            float4 rl = make_float4(aL.x * d2, aL.y * d2, aL.z * d2, aL.w * d2);
            float4 rh = make_float4(aH.x * d2, aH.y * d2, aH.z * d2, aH.w * d2);
            const uint2 pl = f4_to_h4(rl), ph = f4_to_h4(rh);
            uint4 o; o.x = pl.x; o.y = pl.y; o.z = ph.x; o.w = ph.y;
            ((uint4*)out)[(size_t)n * 4 + q] = o;
        }
    } else {
        // redistribute: lane c wants feats 4c..4c+3 = chunk c>>1, half c&1
        const int lane = threadIdx.x & 63;
        const int src = (lane & ~7) | (c >> 1);
        const float s0 = __shfl(aL.x, src), s1 = __shfl(aL.y, src);
        const float s2 = __shfl(aL.z, src), s3 = __shfl(aL.w, src);
        const float s4 = __shfl(aH.x, src), s5 = __shfl(aH.y, src);
        const float s6 = __shfl(aH.z, src), s7 = __shfl(aH.w, src);
        const float4 acc = (c & 1) ? make_float4(s4, s5, s6, s7)
                                   : make_float4(s0, s1, s2, s3);
        float4 r;
        if (MODE == 0) {
            r.x = acc.x * d; r.y = acc.y * d; r.z = acc.z * d; r.w = acc.w * d;
        } else {
            const float a1 = c1[n], a2 = c2[n];
            const float4 w1 = ((const float4*)v1)[c];
            const float4 w2 = ((const float4*)v2)[c];
            const float4 bb = ((const float4*)bv)[c];
            r.x = fmaf(acc.x, d, fmaf(a1, w1.x, fmaf(a2, w2.x, bb.x)));
            r.y = fmaf(acc.y, d, fmaf(a1, w1.y, fmaf(a2, w2.y, bb.y)));
            r.z = fmaf(acc.z, d, fmaf(a1, w1.z, fmaf(a2, w2.z, bb.z)));
            r.w = fmaf(acc.w, d, fmaf(a1, w1.w, fmaf(a2, w2.w, bb.w)));
        }
        ((float4*)out)[idx] = r;
    }
}

// Width-1 pull: out[n] = dis[n]*(in[n] + sum in[src]); optional outd = out*dis.
__device__ __forceinline__ void agg1_body(const float* __restrict__ in,
                                          const u16* __restrict__ mq,
                                          const u16* __restrict__ ell,
                                          const float* __restrict__ dis,
                                          float* __restrict__ out,
                                          float* __restrict__ outd, int blk0) {
    const int n = (blockIdx.x - blk0) * 256 + threadIdx.x;
    if (n >= NN) return;
    float acc = in[n];
    const int m8 = mq[n];
    const iv4* ip = (const iv4*)(ell + (size_t)n * CAP);
    for (int t = 0; t < m8; ++t) {
        const iv4 s = ip[t];
        const unsigned ux = (unsigned)s.x, uy = (unsigned)s.y;
        const unsigned uz = (unsigned)s.z, uw = (unsigned)s.w;
        acc += ((in[ux & 0xFFFFu] + in[ux >> 16]) + (in[uy & 0xFFFFu] + in[uy >> 16]))
             + ((in[uz & 0xFFFFu] + in[uz >> 16]) + (in[uw & 0xFFFFu] + in[uw >> 16]));
    }
    const float r = dis[n] * acc;
    out[n] = r;
    if (outd) outd[n] = r * dis[n];
}

// Pre-agg (fp16 gathers, fp32 out) + folded c1 + W234 = W2@W34, v2 = b2@W34.
__global__ void agg_pre_kernel(const uint4* __restrict__ Xh, const u16* __restrict__ mq,
                               const u16* __restrict__ ell, const float* __restrict__ dis,
                               float* __restrict__ Bb, float* __restrict__ c1,
                               float* __restrict__ c1d,
                               const float* __restrict__ W2, const float* __restrict__ b2,
                               const float* __restrict__ W34, float* __restrict__ W234,
                               float* __restrict__ v2) {
    if (blockIdx.x < AGB) {
        agg32h_body<0>(Xh, mq, ell, dis, nullptr, nullptr, nullptr, nullptr, nullptr, Bb);
    } else if (blockIdx.x < AGB + C1B) {
        agg1_body(dis, mq, ell, dis, c1, c1d, AGB);
    } else {
        const int wid = (blockIdx.x - AGB - C1B) * 256 + threadIdx.x;
        if (wid < 3072) {                       // W234[r][j], lanes share r
            const int r = wid >> 5, j = wid & 31;
            float a = 0.f;
#pragma unroll 8
            for (int k = 0; k < 128; ++k) a = fmaf(W2[r * 128 + k], W34[k * 32 + j], a);
            W234[wid] = a;
        } else if (wid < 3104) {
            const int j = wid - 3072;
            float a = 0.f;
#pragma unroll 8
            for (int k = 0; k < 128; ++k) a = fmaf(b2[k], W34[k * 32 + j], a);
            v2[j] = a;
        }
    }
}

// Hop 1 (half->half) + folded c2 = A.(c1*dis).
__global__ void agg_hop1_kernel(const uint4* __restrict__ Ha, const u16* __restrict__ mq,
                                const u16* __restrict__ ell, const float* __restrict__ dis,
                                uint4* __restrict__ Hb, const float* __restrict__ c1d,
                                float* __restrict__ c2) {
    if (blockIdx.x < AGB)
        agg32h_body<1>(Ha, mq, ell, dis, nullptr, nullptr, nullptr, nullptr, nullptr, Hb);
    else
        agg1_body(c1d, mq, ell, dis, c2, nullptr, AGB);
}

// Hop 2 (half->half).
__global__ void agg_hop2_kernel(const uint4* __restrict__ Hb, const u16* __restrict__ mq,
                                const u16* __restrict__ ell, const float* __restrict__ dis,
                                uint4* __restrict__ Ha) {
    agg32h_body<1>(Hb, mq, ell, dis, nullptr, nullptr, nullptr, nullptr, nullptr, Ha);
}

// Hop 3 (half->fp32) + rank-1 fixups.
__global__ void agg_hop3_kernel(const uint4* __restrict__ Ha, const u16* __restrict__ mq,
                                const u16* __restrict__ ell, const float* __restrict__ dis,
                                const float* __restrict__ c1, const float* __restrict__ c2,
                                const float* __restrict__ v1, const float* __restrict__ v2,
                                const float* __restrict__ bv, float* __restrict__ out) {
    agg32h_body<2>(Ha, mq, ell, dis, c1, c2, v1, v2, bv, out);
}

// Fused dense path: h1d = relu(Xa@W1+b1)*dis (LDS), g = h1d@W234 -> G (fp16).
// 8 accs/thread max; __launch_bounds__(192,2) -> no spill (r13-proven).
__global__ void __launch_bounds__(192, 2)
gemm_fused_kernel(const float* __restrict__ X, const float* __restrict__ W1,
                  const float* __restrict__ b1, const float* __restrict__ dis,
                  const float* __restrict__ W234, uint2* __restrict__ G) {
    constexpr int NPB = 16, RSX = 36, RSH = 104;
    __shared__ float xs[NPB * RSX];
    __shared__ float hsm[NPB * RSH];
    const int tid = threadIdx.x;
    const int n0  = blockIdx.x * NPB;

    const float4* Xv = (const float4*)(X + (size_t)n0 * 32);
    for (int i = tid; i < NPB * 8; i += 192) {
        const int nl = i >> 3, r = i & 7;
        float4 v = make_float4(0.f, 0.f, 0.f, 0.f);
        if (n0 + nl < NN) v = Xv[nl * 8 + r];
        *(float4*)(xs + nl * RSX + r * 4) = v;
    }
    __syncthreads();

    {   // phase A: 29 -> 96, relu(+b1)*dis, result to LDS
        const int cg = tid % 24, g = tid / 24;
        const float* x0 = xs + (2 * g) * RSX;
        const float* x1 = x0 + RSX;
        const float4* Wv = (const float4*)W1;
        float4 a0 = make_float4(0.f, 0.f, 0.f, 0.f);
        float4 a1 = make_float4(0.f, 0.f, 0.f, 0.f);
#pragma unroll
        for (int k = 0; k < 29; ++k) {
            const float4 w = Wv[k * 24 + cg];
            const float v0 = x0[k], v1 = x1[k];
            a0.x = fmaf(v0, w.x, a0.x); a0.y = fmaf(v0, w.y, a0.y);
            a0.z = fmaf(v0, w.z, a0.z); a0.w = fmaf(v0, w.w, a0.w);
            a1.x = fmaf(v1, w.x, a1.x); a1.y = fmaf(v1, w.y, a1.y);
            a1.z = fmaf(v1, w.z, a1.z); a1.w = fmaf(v1, w.w, a1.w);
        }
        const float4 bb = ((const float4*)b1)[cg];
#pragma unroll
        for (int h = 0; h < 2; ++h) {
            const int nl = 2 * g + h, node = n0 + nl;
            const float d = (node < NN) ? dis[node] : 0.f;
            const float4 a = h ? a1 : a0;
            float4 r;
            r.x = fmaxf(a.x + bb.x, 0.f) * d; r.y = fmaxf(a.y + bb.y, 0.f) * d;
            r.z = fmaxf(a.z + bb.z, 0.f) * d; r.w = fmaxf(a.w + bb.w, 0.f) * d;
            *(float4*)(hsm + nl * RSH + cg * 4) = r;
        }
    }
    __syncthreads();

    if (tid < 128) {  // phase B: 96 -> 32 raw, store fp16
        const int nl = tid >> 3, cg = tid & 7;
        const float* hr = hsm + nl * RSH;
        const float4* Wv = (const float4*)W234;
        float4 a = make_float4(0.f, 0.f, 0.f, 0.f);
#pragma unroll 8
        for (int k = 0; k < 96; ++k) {
            const float4 w = Wv[k * 8 + cg];
            const float v = hr[k];
            a.x = fmaf(v, w.x, a.x); a.y = fmaf(v, w.y, a.y);
            a.z = fmaf(v, w.z, a.z); a.w = fmaf(v, w.w, a.w);
        }
        const int node = n0 + nl;
        if (node < NN) G[(size_t)node * 8 + cg] = f4_to_h4(a);
    }
}

extern "C" void kernel_launch(void* const* d_in, const int* in_sizes, int n_in,
                              void* d_out, int out_size, void* d_ws, size_t ws_size,
                              hipStream_t stream) {
    const float* x  = (const float*)d_in[0];
    const int*   ei = (const int*)d_in[1];           // int32 (harness converts)
    const float* W1 = (const float*)d_in[2]; const float* b1 = (const float*)d_in[3];
    const float* W2 = (const float*)d_in[4]; const float* b2 = (const float*)d_in[5];
    const float* W3 = (const float*)d_in[6]; const float* b3 = (const float*)d_in[7];
    const float* W4 = (const float*)d_in[8]; const float* b4p = (const float*)d_in[9];
    float* outp = (float*)d_out;

    const int E = in_sizes[1] / 2;          // 800000
    const int* row = ei;
    const int* col = ei + E;

    // Workspace (4B elems, 64B-aligned sections), ~30 MB:
    int*   cnt  = (int*)d_ws;                       // 50048*32 ints (padded, 6.4 MB)
    float* dis  = (float*)(cnt + 50048 * CST);      // 50064 floats (uses [NN])
    u16*   ell  = (u16*)(dis + 50064);              // NN*CAP u16 = 1,600,000 ints
    u16*   mq   = (u16*)((int*)ell + 1600000);      // 50048 u16 = 25024 ints
    float* c1   = (float*)((int*)mq + 25024);       // 50064
    float* c1d  = c1 + 50064;                       // 50064 (uses [NN])
    float* c2   = c1d + 50064;                      // 50064
    float* W34  = c2 + 50064;                       // 4096
    float* W234 = W34 + 4096;                       // 3072
    float* v1   = W234 + 3072;                      // 32
    float* v2   = v1 + 32;                          // 32
    unsigned* Xh = (unsigned*)(v2 + 32);            // (NN+1)*16 uints (fp16 x-hat)
    float* Bb   = (float*)(Xh + 800032);            // NN*32 + pad = 1600064
    unsigned* Ha = (unsigned*)(Bb + 1600064);       // (NN+1)*16 uints (fp16 rows)
    unsigned* Hb = Ha + 800032;                     // (NN+1)*16 uints

    // 1. zero padded counters (6.4 MB)
    hipMemsetAsync(cnt, 0, (size_t)50048 * CST * sizeof(int), stream);
    // 2. build ELL, XCD-affine (8 groups x 256 blocks, int4 edge loads)
    place_x_kernel<<<8 * PXB, 256, 0, stream>>>(row, col, cnt, ell, E);
    // 3. dis + mq + pad + Xh(fp16) + sentinels; extra: W34 + v1
    prep_all_kernel<<<PREPB + W34XB, 256, 0, stream>>>(cnt, ell, x, dis, mq, Xh,
                                                       Ha, Hb, c1d, W3, W4, b3, W34, v1);
    // 4. pre-agg fp16-gather (Xh->Bb fp32) + folded c1; extra: W234 + v2
    agg_pre_kernel<<<AGB + C1B + W234XB, 256, 0, stream>>>((const uint4*)Xh, mq, ell, dis,
                                                           Bb, c1, c1d,
                                                           W2, b2, W34, W234, v2);
    // 5. fused dense: Ha(fp16) = relu(Bb@W1+b1)*dis @ W234
    gemm_fused_kernel<<<(NN + 15) / 16, 192, 0, stream>>>(Bb, W1, b1, dis, W234,
                                                          (uint2*)Ha);
    // 6. hop 1 (Ha->Hb, 16B-lane fp16 gathers) + folded c2
    agg_hop1_kernel<<<AGB + C1B, 256, 0, stream>>>((const uint4*)Ha, mq, ell, dis,
                                                   (uint4*)Hb, c1d, c2);
    // 7. hop 2 (Hb->Ha)
    agg_hop2_kernel<<<AGB, 256, 0, stream>>>((const uint4*)Hb, mq, ell, dis, (uint4*)Ha);
    // 8. hop 3 + rank-1 fixups (Ha->out, fp32)
    agg_hop3_kernel<<<AGB, 256, 0, stream>>>((const uint4*)Ha, mq, ell, dis,
                                             c1, c2, v1, v2, b4p, outp);
}